// Round 2
// baseline (1668.437 us; speedup 1.0000x reference)
//
#include <hip/hip_runtime.h>
#include <stdint.h>

using u16 = unsigned short;
using bf16x8 = __attribute__((ext_vector_type(8))) short;
using f32x4 = __attribute__((ext_vector_type(4))) float;

#define B_N 16
#define L_N 1024
#define D_N 512
#define E_N (16LL * 1024 * 512)
#define W_N (512LL * 512)
#define OUTW 3584
#define SCALE_F 0.04419417382415922f

__device__ __forceinline__ u16 f2b(float f) {
  union { float f; uint32_t u; } c; c.f = f;
  uint32_t r = c.u + 0x7fffu + ((c.u >> 16) & 1u);
  return (u16)(r >> 16);
}

__device__ __forceinline__ void async16(const u16* g, u16* l) {
  __builtin_amdgcn_global_load_lds((const __attribute__((address_space(1))) void*)g,
                                   (__attribute__((address_space(3))) void*)l, 16, 0, 0);
}

struct Ptrs24 { const float* p[24]; };

// ---- convert all fp32 inputs (3 activations + 21 weights) to bf16 in ws ----
__global__ __launch_bounds__(256) void convert_inputs_k(Ptrs24 ptrs, u16* __restrict__ dstX,
                                                        u16* __restrict__ dstW) {
  const long long total4 = (3 * E_N + 21 * W_N) >> 2;
  for (long long i = (long long)blockIdx.x * blockDim.x + threadIdx.x; i < total4;
       i += (long long)gridDim.x * blockDim.x) {
    long long e = i << 2;
    const float* src; u16* dst; long long off;
    if (e < 3 * E_N) {
      int t = (int)(e / E_N); off = e - (long long)t * E_N;
      src = ptrs.p[t]; dst = dstX + (long long)t * E_N;
    } else {
      long long e2 = e - 3 * E_N;
      int t = (int)(e2 / W_N); off = e2 - (long long)t * W_N;
      src = ptrs.p[3 + t]; dst = dstW + (long long)t * W_N;
    }
    float4 v = *(const float4*)(src + off);
    ushort4 o; o.x = f2b(v.x); o.y = f2b(v.y); o.z = f2b(v.z); o.w = f2b(v.w);
    *(ushort4*)(dst + off) = o;
  }
}

// ---- init d_out: slots 0..2 = inputs, 3..5 = residual sums, 6 = 0 ----
__global__ __launch_bounds__(256) void init_out_k(const float* __restrict__ txt,
                                                  const float* __restrict__ au,
                                                  const float* __restrict__ vi,
                                                  float* __restrict__ out) {
  long long i = (long long)blockIdx.x * 256 + threadIdx.x;  // E/4 threads
  long long e = i << 2;
  int a = (int)(e & (D_N - 1));
  long long bl = e >> 9;
  float4 t = *(const float4*)(txt + e);
  float4 u = *(const float4*)(au + e);
  float4 v = *(const float4*)(vi + e);
  float* o = out + bl * OUTW + a;
  *(float4*)(o) = t;
  *(float4*)(o + 512) = u;
  *(float4*)(o + 1024) = v;
  float4 r;
  r.x = t.x + u.x; r.y = t.y + u.y; r.z = t.z + u.z; r.w = t.w + u.w;
  *(float4*)(o + 1536) = r;                                   // ta residual: txt+au
  r.x = t.x + v.x; r.y = t.y + v.y; r.z = t.z + v.z; r.w = t.w + v.w;
  *(float4*)(o + 2048) = r;                                   // tv residual: txt+vi
  r.x = u.x + v.x; r.y = u.y + v.y; r.z = u.z + v.z; r.w = u.w + v.w;
  *(float4*)(o + 2560) = r;                                   // av residual: au+vi
  r.x = 0.f; r.y = 0.f; r.z = 0.f; r.w = 0.f;
  *(float4*)(o + 3072) = r;                                   // tav: no residual
}

// ---- read av slot (5) of d_out, convert to bf16 for cross-attn queries ----
__global__ __launch_bounds__(256) void conv_av_k(const float* __restrict__ out,
                                                 u16* __restrict__ avb) {
  long long i = (long long)blockIdx.x * 256 + threadIdx.x;
  long long e = i << 2;
  int a = (int)(e & (D_N - 1));
  long long bl = e >> 9;
  float4 v = *(const float4*)(out + bl * OUTW + 2560 + a);
  ushort4 o; o.x = f2b(v.x); o.y = f2b(v.y); o.z = f2b(v.z); o.w = f2b(v.w);
  *(ushort4*)(avb + e) = o;
}

// ---- batched bf16 transpose (L,D) -> (D,L) ----
__global__ void transpose_k(const u16* __restrict__ in, u16* __restrict__ out) {
  __shared__ u16 tile[32][33];
  const long long b = blockIdx.z;
  const u16* src = in + b * (long long)L_N * D_N;
  u16* dst = out + b * (long long)L_N * D_N;
  const int c0 = blockIdx.x * 32, r0 = blockIdx.y * 32;
  const int tx = threadIdx.x, ty = threadIdx.y;
#pragma unroll
  for (int i = 0; i < 4; i++)
    tile[ty + i * 8][tx] = src[(long long)(r0 + ty + i * 8) * D_N + c0 + tx];
  __syncthreads();
#pragma unroll
  for (int i = 0; i < 4; i++)
    dst[(long long)(c0 + ty + i * 8) * L_N + r0 + tx] = tile[tx][ty + i * 8];
}

// ---- row softmax over fp32 S (1024 cols), write bf16 P ----
__global__ __launch_bounds__(256) void softmax_k(const float* __restrict__ S,
                                                 u16* __restrict__ P) {
  const long long row = blockIdx.x;
  const float* s = S + row * 1024;
  u16* p = P + row * 1024;
  const int tid = threadIdx.x;
  float v[4];
#pragma unroll
  for (int i = 0; i < 4; i++) v[i] = s[tid + i * 256] * SCALE_F;
  float m = fmaxf(fmaxf(v[0], v[1]), fmaxf(v[2], v[3]));
#pragma unroll
  for (int off = 32; off; off >>= 1) m = fmaxf(m, __shfl_xor(m, off));
  __shared__ float redm[4], reds[4];
  if ((tid & 63) == 0) redm[tid >> 6] = m;
  __syncthreads();
  m = fmaxf(fmaxf(redm[0], redm[1]), fmaxf(redm[2], redm[3]));
  float e[4], sum = 0.f;
#pragma unroll
  for (int i = 0; i < 4; i++) { e[i] = __expf(v[i] - m); sum += e[i]; }
#pragma unroll
  for (int off = 32; off; off >>= 1) sum += __shfl_xor(sum, off);
  if ((tid & 63) == 0) reds[tid >> 6] = sum;
  __syncthreads();
  sum = reds[0] + reds[1] + reds[2] + reds[3];
  float inv = 1.0f / sum;
#pragma unroll
  for (int i = 0; i < 4; i++) p[tid + i * 256] = f2b(e[i] * inv);
}

// ---- m97-style bf16 MFMA GEMM: C = A @ B^T.  A:(M,K) row-major, B:(N,K) row-major.
// OMODE 0: bf16 out; 1: fp32 out; 2: fp32 accumulate (+=). Grid: (M/128, N/128, batch).
template <int OMODE>
__global__ __launch_bounds__(256) void gemm_bt(const u16* __restrict__ A,
                                               const u16* __restrict__ Bm,
                                               void* __restrict__ Cv, int K,
                                               long long sA, long long sB, long long sC,
                                               int ldc, int ccol) {
  __shared__ __align__(16) u16 lA[128 * 32];
  __shared__ __align__(16) u16 lB[128 * 32];
  const int z = blockIdx.z;
  A += (long long)z * sA;
  Bm += (long long)z * sB;
  const int m0 = blockIdx.x * 128, n0 = blockIdx.y * 128;
  const int tid = threadIdx.x;
  const int wave = tid >> 6, lane = tid & 63;
  const int fr = lane & 15, kb = lane >> 4;
  const int wm = (wave >> 1) * 64, wn = (wave & 1) * 64;

  f32x4 acc[4][4];
#pragma unroll
  for (int i = 0; i < 4; i++)
#pragma unroll
    for (int j = 0; j < 4; j++) acc[i][j] = (f32x4){0.f, 0.f, 0.f, 0.f};

  const int e0 = tid * 8, e1 = (256 + tid) * 8;
  const u16* Ap0 = A + (long long)(m0 + (e0 >> 5)) * K + (e0 & 31);
  const u16* Ap1 = A + (long long)(m0 + (e1 >> 5)) * K + (e1 & 31);
  const u16* Bp0 = Bm + (long long)(n0 + (e0 >> 5)) * K + (e0 & 31);
  const u16* Bp1 = Bm + (long long)(n0 + (e1 >> 5)) * K + (e1 & 31);
  u16* lA0 = lA + wave * 64 * 8;
  u16* lA1 = lA + (256 + wave * 64) * 8;
  u16* lB0 = lB + wave * 64 * 8;
  u16* lB1 = lB + (256 + wave * 64) * 8;

  const int nk = K >> 5;
  for (int kt = 0; kt < nk; ++kt) {
    __syncthreads();
    async16(Ap0, lA0); async16(Ap1, lA1);
    async16(Bp0, lB0); async16(Bp1, lB1);
    Ap0 += 32; Ap1 += 32; Bp0 += 32; Bp1 += 32;
    __syncthreads();
    bf16x8 af[4], bfr[4];
#pragma unroll
    for (int i = 0; i < 4; i++) af[i] = *(const bf16x8*)&lA[(wm + i * 16 + fr) * 32 + kb * 8];
#pragma unroll
    for (int j = 0; j < 4; j++) bfr[j] = *(const bf16x8*)&lB[(wn + j * 16 + fr) * 32 + kb * 8];
#pragma unroll
    for (int i = 0; i < 4; i++)
#pragma unroll
      for (int j = 0; j < 4; j++)
        acc[i][j] = __builtin_amdgcn_mfma_f32_16x16x32_bf16(af[i], bfr[j], acc[i][j], 0, 0, 0);
  }

  const int crow = (lane >> 4) * 4;
  const int ccl = lane & 15;
  if (OMODE == 0) {
    u16* C = (u16*)Cv + (long long)z * sC;
#pragma unroll
    for (int i = 0; i < 4; i++)
#pragma unroll
      for (int j = 0; j < 4; j++)
#pragma unroll
        for (int r = 0; r < 4; r++)
          C[(long long)(m0 + wm + i * 16 + crow + r) * ldc + ccol + n0 + wn + j * 16 + ccl] =
              f2b(acc[i][j][r]);
  } else if (OMODE == 1) {
    float* C = (float*)Cv + (long long)z * sC;
#pragma unroll
    for (int i = 0; i < 4; i++)
#pragma unroll
      for (int j = 0; j < 4; j++)
#pragma unroll
        for (int r = 0; r < 4; r++)
          C[(long long)(m0 + wm + i * 16 + crow + r) * ldc + ccol + n0 + wn + j * 16 + ccl] =
              acc[i][j][r];
  } else {
    float* C = (float*)Cv + (long long)z * sC;
#pragma unroll
    for (int i = 0; i < 4; i++)
#pragma unroll
      for (int j = 0; j < 4; j++)
#pragma unroll
        for (int r = 0; r < 4; r++) {
          long long idx = (long long)(m0 + wm + i * 16 + crow + r) * ldc + ccol + n0 + wn + j * 16 + ccl;
          C[idx] += acc[i][j][r];
        }
  }
}

extern "C" void kernel_launch(void* const* d_in, const int* in_sizes, int n_in,
                              void* d_out, int out_size, void* d_ws, size_t ws_size,
                              hipStream_t stream) {
  (void)in_sizes; (void)n_in; (void)out_size;
  float* out = (float*)d_out;

  // Workspace layout (bytes): guard against ws_size overflow — if the harness
  // workspace is smaller than required, fail cleanly (wrong output) instead of
  // faulting the device with OOB writes.
  const long long need =
      (3 * E_N + 21 * W_N + 5 * E_N) * 2 /*bf16 bufs*/ +
      (long long)B_N * L_N * L_N * 4 /*S fp32*/ +
      (long long)B_N * L_N * L_N * 2 /*P bf16*/;
  Ptrs24 ptrs;
  for (int i = 0; i < 24; i++) ptrs.p[i] = (const float*)d_in[i];

  // init_out only touches d_out (correctly sized by harness) — always safe.
  init_out_k<<<8192, 256, 0, stream>>>(ptrs.p[0], ptrs.p[1], ptrs.p[2], out);
  if ((long long)ws_size < need) return;  // diagnostic: absmax will show attn slots missing

  u16* xb = (u16*)d_ws;          // 3*E bf16 activations (txt, au, vi)
  u16* wb = xb + 3 * E_N;        // 21*W bf16 weights
  u16* qb = wb + 21 * W_N;       // E
  u16* kbuf = qb + E_N;          // E
  u16* vtmp = kbuf + E_N;        // E
  u16* vt = vtmp + E_N;          // E (V transposed per batch: (D,L))
  u16* avb = vt + E_N;           // E (bf16 copy of av for cross-attn queries)
  float* S = (float*)(avb + E_N);                 // B*L*L fp32 scores
  u16* P = (u16*)(S + (long long)B_N * L_N * L_N);  // B*L*L bf16 probs

  convert_inputs_k<<<4096, 256, 0, stream>>>(ptrs, xb, wb);

  const u16* X[3] = {xb, xb + E_N, xb + 2 * E_N};  // txt, au, vi

  auto proj = [&](const u16* Xin, int widx, u16* Out) {
    gemm_bt<0><<<dim3(128, 4, 1), 256, 0, stream>>>(
        Xin, wb + (long long)widx * W_N, (void*)Out, 512, 0LL, 0LL, 0LL, 512, 0);
  };
  auto attn = [&](const u16* qin, int qw, const u16* kin, int kw, const u16* vin, int vw,
                  int slot) {
    proj(kin, kw, kbuf);
    proj(qin, qw, qb);
    proj(vin, vw, vtmp);
    transpose_k<<<dim3(16, 32, 16), dim3(32, 8), 0, stream>>>(vtmp, vt);
    gemm_bt<1><<<dim3(8, 8, 16), 256, 0, stream>>>(
        qb, kbuf, (void*)S, 512, (long long)L_N * D_N, (long long)L_N * D_N,
        (long long)L_N * L_N, 1024, 0);
    softmax_k<<<16384, 256, 0, stream>>>(S, P);
    gemm_bt<2><<<dim3(8, 4, 16), 256, 0, stream>>>(
        P, vt, (void*)out, 1024, (long long)L_N * L_N, (long long)D_N * L_N,
        (long long)L_N * OUTW, OUTW, slot * D_N);
  };

  // sym blocks: {m1, m2, weight base (within 21), out slot}
  // ta: (txt,au) -> slot 3 ; va: (vi,au) -> slot 5 ; tv: (txt,vi) -> slot 4
  const int m1s[3] = {0, 2, 0}, m2s[3] = {1, 1, 2}, wbase[3] = {0, 6, 12}, slots[3] = {3, 5, 4};
  for (int b = 0; b < 3; b++) {
    // attn1: s1 = softmax(q2@k1^T), o1 = s1@v1 ; q2=m2@Wqy, k1=m1@Wkx, v1=m1@Wvx
    attn(X[m2s[b]], wbase[b] + 4, X[m1s[b]], wbase[b] + 0, X[m1s[b]], wbase[b] + 2, slots[b]);
    // attn2: s2 = softmax(q1@k2^T), o2 = s2@v2 ; q1=m1@Wqx, k2=m2@Wky, v2=m2@Wvy
    attn(X[m1s[b]], wbase[b] + 1, X[m2s[b]], wbase[b] + 3, X[m2s[b]], wbase[b] + 5, slots[b]);
  }

  // cross attention: x = txt, queries = av (slot 5, complete at this point)
  conv_av_k<<<8192, 256, 0, stream>>>(out, avb);
  // weights: tav_k -> wb[18], tav_q -> wb[19], tav_v -> wb[20]
  attn(avb, 19, X[0], 18, X[0], 20, 6);
}

// Round 4
// 1569.752 us; speedup vs baseline: 1.0629x; 1.0629x over previous
//
#include <hip/hip_runtime.h>
#include <stdint.h>

using u16 = unsigned short;
using bf16x8 = __attribute__((ext_vector_type(8))) short;
using f32x4 = __attribute__((ext_vector_type(4))) float;

#define B_N 16
#define L_N 1024
#define D_N 512
#define E_N (16LL * 1024 * 512)
#define W_N (512LL * 512)
#define OUTW 3584
#define SCALE_F 0.04419417382415922f

__device__ __forceinline__ u16 f2b(float f) {
  union { float f; uint32_t u; } c; c.f = f;
  uint32_t r = c.u + 0x7fffu + ((c.u >> 16) & 1u);
  return (u16)(r >> 16);
}

__device__ __forceinline__ void async16(const u16* g, u16* l) {
  __builtin_amdgcn_global_load_lds((const __attribute__((address_space(1))) void*)g,
                                   (__attribute__((address_space(3))) void*)l, 16, 0, 0);
}

struct Ptrs24 { const float* p[24]; };

// ---- fused: convert activations to bf16 + init d_out slots ----
__global__ __launch_bounds__(256) void act_init_k(const float* __restrict__ txt,
                                                  const float* __restrict__ au,
                                                  const float* __restrict__ vi,
                                                  u16* __restrict__ xb,
                                                  float* __restrict__ out) {
  long long i = (long long)blockIdx.x * 256 + threadIdx.x;  // E/4 threads
  long long e = i << 2;
  int a = (int)(e & (D_N - 1));
  long long bl = e >> 9;
  float4 t = *(const float4*)(txt + e);
  float4 u = *(const float4*)(au + e);
  float4 v = *(const float4*)(vi + e);
  ushort4 o;
  o.x = f2b(t.x); o.y = f2b(t.y); o.z = f2b(t.z); o.w = f2b(t.w);
  *(ushort4*)(xb + e) = o;
  o.x = f2b(u.x); o.y = f2b(u.y); o.z = f2b(u.z); o.w = f2b(u.w);
  *(ushort4*)(xb + E_N + e) = o;
  o.x = f2b(v.x); o.y = f2b(v.y); o.z = f2b(v.z); o.w = f2b(v.w);
  *(ushort4*)(xb + 2 * E_N + e) = o;
  float* op = out + bl * OUTW + a;
  *(float4*)(op) = t;
  *(float4*)(op + 512) = u;
  *(float4*)(op + 1024) = v;
  float4 r;
  r.x = t.x + u.x; r.y = t.y + u.y; r.z = t.z + u.z; r.w = t.w + u.w;
  *(float4*)(op + 1536) = r;                                  // ta residual: txt+au
  r.x = t.x + v.x; r.y = t.y + v.y; r.z = t.z + v.z; r.w = t.w + v.w;
  *(float4*)(op + 2048) = r;                                  // tv residual: txt+vi
  r.x = u.x + v.x; r.y = u.y + v.y; r.z = u.z + v.z; r.w = u.w + v.w;
  *(float4*)(op + 2560) = r;                                  // av residual: au+vi
  r.x = 0.f; r.y = 0.f; r.z = 0.f; r.w = 0.f;
  *(float4*)(op + 3072) = r;                                  // tav: no residual
}

// ---- convert 21 weights to bf16, PERMUTED into input-grouped order ----
// wb order: [txt-grp: ta_kx ta_qx ta_vx tv_kx tv_qx tv_vx tav_k tav_v]
//           [au-grp : ta_ky ta_qy ta_vy va_ky va_qy va_vy]
//           [vi-grp : va_kx va_qx va_vx tv_ky tv_qy tv_vy]
//           [av-grp : tav_q]
__global__ __launch_bounds__(256) void convert_w_k(Ptrs24 ptrs, u16* __restrict__ wb) {
  const int perm[21] = {0, 1, 2, 12, 13, 14, 18, 20,
                        3, 4, 5, 9, 10, 11,
                        6, 7, 8, 15, 16, 17,
                        19};
  long long i = (long long)blockIdx.x * 256 + threadIdx.x;
  const long long total4 = (21 * W_N) >> 2;
  if (i >= total4) return;
  long long e = i << 2;
  int t = (int)(e / W_N);
  long long off = e - (long long)t * W_N;
  const float* src = ptrs.p[3 + perm[t]];
  float4 v = *(const float4*)(src + off);
  ushort4 o; o.x = f2b(v.x); o.y = f2b(v.y); o.z = f2b(v.z); o.w = f2b(v.w);
  *(ushort4*)(wb + (long long)t * W_N + off) = o;
}

// ---- read av slot (5) of d_out, convert to bf16 for cross-attn queries ----
__global__ __launch_bounds__(256) void conv_av_k(const float* __restrict__ out,
                                                 u16* __restrict__ avb) {
  long long i = (long long)blockIdx.x * 256 + threadIdx.x;
  long long e = i << 2;
  int a = (int)(e & (D_N - 1));
  long long bl = e >> 9;
  float4 v = *(const float4*)(out + bl * OUTW + 2560 + a);
  ushort4 o; o.x = f2b(v.x); o.y = f2b(v.y); o.z = f2b(v.z); o.w = f2b(v.w);
  *(ushort4*)(avb + e) = o;
}

// ---- batched bf16 transpose: strided (B*L, 512) slice -> (B, 512, 1024) ----
__global__ void transpose_k(const u16* __restrict__ in, int ldin, u16* __restrict__ out) {
  __shared__ u16 tile[32][33];
  const int b = blockIdx.z;
  const u16* src = in + (long long)b * 1024 * ldin;
  u16* dst = out + (long long)b * 512 * 1024;
  const int c0 = blockIdx.x * 32, r0 = blockIdx.y * 32;
  const int tx = threadIdx.x, ty = threadIdx.y;
#pragma unroll
  for (int i = 0; i < 4; i++)
    tile[ty + i * 8][tx] = src[(long long)(r0 + ty + i * 8) * ldin + c0 + tx];
  __syncthreads();
#pragma unroll
  for (int i = 0; i < 4; i++)
    dst[(long long)(c0 + ty + i * 8) * 1024 + r0 + tx] = tile[tx][ty + i * 8];
}

// ---- row softmax over fp32 S (1024 cols), write bf16 P ----
__global__ __launch_bounds__(256) void softmax_k(const float* __restrict__ S,
                                                 u16* __restrict__ P) {
  const long long row = blockIdx.x;
  const float4* s = (const float4*)(S + row * 1024);
  const int tid = threadIdx.x;
  float4 v = s[tid];
  v.x *= SCALE_F; v.y *= SCALE_F; v.z *= SCALE_F; v.w *= SCALE_F;
  float m = fmaxf(fmaxf(v.x, v.y), fmaxf(v.z, v.w));
#pragma unroll
  for (int off = 32; off; off >>= 1) m = fmaxf(m, __shfl_xor(m, off));
  __shared__ float redm[4], reds[4];
  if ((tid & 63) == 0) redm[tid >> 6] = m;
  __syncthreads();
  m = fmaxf(fmaxf(redm[0], redm[1]), fmaxf(redm[2], redm[3]));
  float e0 = __expf(v.x - m), e1 = __expf(v.y - m), e2 = __expf(v.z - m), e3 = __expf(v.w - m);
  float sum = e0 + e1 + e2 + e3;
#pragma unroll
  for (int off = 32; off; off >>= 1) sum += __shfl_xor(sum, off);
  if ((tid & 63) == 0) reds[tid >> 6] = sum;
  __syncthreads();
  sum = reds[0] + reds[1] + reds[2] + reds[3];
  float inv = 1.0f / sum;
  ushort4 o;
  o.x = f2b(e0 * inv); o.y = f2b(e1 * inv); o.z = f2b(e2 * inv); o.w = f2b(e3 * inv);
  *(ushort4*)(P + row * 1024 + tid * 4) = o;
}

// ---- m97-style bf16 MFMA GEMM: C = A @ B^T.
// A:(M,K) rows at stride lda, B:(N,K) rows at stride ldb.
// OMODE 0: bf16 out; 1: fp32 out; 2: fp32 accumulate (+=). Grid: (M/128, N/128, batch).
template <int OMODE>
__global__ __launch_bounds__(256) void gemm_bt(const u16* __restrict__ A,
                                               const u16* __restrict__ Bm,
                                               void* __restrict__ Cv, int K,
                                               int lda, int ldb,
                                               long long sA, long long sB, long long sC,
                                               int ldc, int ccol) {
  __shared__ __align__(16) u16 lA[128 * 32];
  __shared__ __align__(16) u16 lB[128 * 32];
  const int z = blockIdx.z;
  A += (long long)z * sA;
  Bm += (long long)z * sB;
  const int m0 = blockIdx.x * 128, n0 = blockIdx.y * 128;
  const int tid = threadIdx.x;
  const int wave = tid >> 6, lane = tid & 63;
  const int fr = lane & 15, kb = lane >> 4;
  const int wm = (wave >> 1) * 64, wn = (wave & 1) * 64;

  f32x4 acc[4][4];
#pragma unroll
  for (int i = 0; i < 4; i++)
#pragma unroll
    for (int j = 0; j < 4; j++) acc[i][j] = (f32x4){0.f, 0.f, 0.f, 0.f};

  const int e0 = tid * 8, e1 = (256 + tid) * 8;
  const u16* Ap0 = A + (long long)(m0 + (e0 >> 5)) * lda + (e0 & 31);
  const u16* Ap1 = A + (long long)(m0 + (e1 >> 5)) * lda + (e1 & 31);
  const u16* Bp0 = Bm + (long long)(n0 + (e0 >> 5)) * ldb + (e0 & 31);
  const u16* Bp1 = Bm + (long long)(n0 + (e1 >> 5)) * ldb + (e1 & 31);
  u16* lA0 = lA + wave * 64 * 8;
  u16* lA1 = lA + (256 + wave * 64) * 8;
  u16* lB0 = lB + wave * 64 * 8;
  u16* lB1 = lB + (256 + wave * 64) * 8;

  const int nk = K >> 5;
  for (int kt = 0; kt < nk; ++kt) {
    __syncthreads();
    async16(Ap0, lA0); async16(Ap1, lA1);
    async16(Bp0, lB0); async16(Bp1, lB1);
    Ap0 += 32; Ap1 += 32; Bp0 += 32; Bp1 += 32;
    __syncthreads();
    bf16x8 af[4], bfr[4];
#pragma unroll
    for (int i = 0; i < 4; i++) af[i] = *(const bf16x8*)&lA[(wm + i * 16 + fr) * 32 + kb * 8];
#pragma unroll
    for (int j = 0; j < 4; j++) bfr[j] = *(const bf16x8*)&lB[(wn + j * 16 + fr) * 32 + kb * 8];
#pragma unroll
    for (int i = 0; i < 4; i++)
#pragma unroll
      for (int j = 0; j < 4; j++)
        acc[i][j] = __builtin_amdgcn_mfma_f32_16x16x32_bf16(af[i], bfr[j], acc[i][j], 0, 0, 0);
  }

  const int crow = (lane >> 4) * 4;
  const int ccl = lane & 15;
  if (OMODE == 0) {
    u16* C = (u16*)Cv + (long long)z * sC;
#pragma unroll
    for (int i = 0; i < 4; i++)
#pragma unroll
      for (int j = 0; j < 4; j++)
#pragma unroll
        for (int r = 0; r < 4; r++)
          C[(long long)(m0 + wm + i * 16 + crow + r) * ldc + ccol + n0 + wn + j * 16 + ccl] =
              f2b(acc[i][j][r]);
  } else if (OMODE == 1) {
    float* C = (float*)Cv + (long long)z * sC;
#pragma unroll
    for (int i = 0; i < 4; i++)
#pragma unroll
      for (int j = 0; j < 4; j++)
#pragma unroll
        for (int r = 0; r < 4; r++)
          C[(long long)(m0 + wm + i * 16 + crow + r) * ldc + ccol + n0 + wn + j * 16 + ccl] =
              acc[i][j][r];
  } else {
    float* C = (float*)Cv + (long long)z * sC;
#pragma unroll
    for (int i = 0; i < 4; i++)
#pragma unroll
      for (int j = 0; j < 4; j++)
#pragma unroll
        for (int r = 0; r < 4; r++) {
          long long idx = (long long)(m0 + wm + i * 16 + crow + r) * ldc + ccol + n0 + wn + j * 16 + ccl;
          C[idx] += acc[i][j][r];
        }
  }
}

extern "C" void kernel_launch(void* const* d_in, const int* in_sizes, int n_in,
                              void* d_out, int out_size, void* d_ws, size_t ws_size,
                              hipStream_t stream) {
  (void)in_sizes; (void)n_in; (void)out_size;
  float* out = (float*)d_out;

  // Workspace layout (elements unless noted):
  //   xb  : 3*E bf16  activations (txt, au, vi)
  //   wb  : 21*W bf16 weights (permuted input-grouped order)
  //   pt  : 8*E bf16  txt projections (16384 x 4096)
  //   pa  : 6*E bf16  au  projections (16384 x 3072)
  //   pv  : 6*E bf16  vi  projections (16384 x 3072)
  //   pav : 1*E bf16  av  projection  (16384 x 512)
  //   vt  : 1*E bf16  V^T scratch (B, 512, 1024)
  //   avb : 1*E bf16  av activation
  //   S   : B*L*L fp32 scores
  //   P   : B*L*L bf16 probs
  const long long SLL = (long long)B_N * L_N * L_N;
  const long long need = (26 * E_N + 21 * W_N) * 2 + SLL * 4 + SLL * 2;

  Ptrs24 ptrs;
  for (int i = 0; i < 24; i++) ptrs.p[i] = (const float*)d_in[i];

  if ((long long)ws_size < need) {
    // fail cleanly (wrong output) rather than fault the device
    act_init_k<<<8192, 256, 0, stream>>>(ptrs.p[0], ptrs.p[1], ptrs.p[2], (u16*)d_ws, out);
    return;
  }

  u16* xb = (u16*)d_ws;
  u16* wb = xb + 3 * E_N;
  u16* pt = wb + 21 * W_N;
  u16* pa = pt + 8 * E_N;
  u16* pv = pa + 6 * E_N;
  u16* pav = pv + 6 * E_N;
  u16* vt = pav + E_N;
  u16* avb = vt + E_N;
  float* S = (float*)(avb + E_N);
  u16* P = (u16*)(S + SLL);

  act_init_k<<<8192, 256, 0, stream>>>(ptrs.p[0], ptrs.p[1], ptrs.p[2], xb, out);
  convert_w_k<<<5376, 256, 0, stream>>>(ptrs, wb);

  // Merged projections: C = X @ Wgrp^T
  gemm_bt<0><<<dim3(128, 32, 1), 256, 0, stream>>>(xb, wb, (void*)pt, 512, 512, 512,
                                                   0LL, 0LL, 0LL, 4096, 0);
  gemm_bt<0><<<dim3(128, 24, 1), 256, 0, stream>>>(xb + E_N, wb + 8 * W_N, (void*)pa, 512,
                                                   512, 512, 0LL, 0LL, 0LL, 3072, 0);
  gemm_bt<0><<<dim3(128, 24, 1), 256, 0, stream>>>(xb + 2 * E_N, wb + 14 * W_N, (void*)pv, 512,
                                                   512, 512, 0LL, 0LL, 0LL, 3072, 0);

  auto attn = [&](const u16* q, int ldq, const u16* k, int ldk, const u16* v, int ldv,
                  int slot) {
    transpose_k<<<dim3(16, 32, 16), dim3(32, 8), 0, stream>>>(v, ldv, vt);
    gemm_bt<1><<<dim3(8, 8, 16), 256, 0, stream>>>(
        q, k, (void*)S, 512, ldq, ldk, (long long)1024 * ldq, (long long)1024 * ldk,
        (long long)L_N * L_N, 1024, 0);
    softmax_k<<<16384, 256, 0, stream>>>(S, P);
    gemm_bt<2><<<dim3(8, 4, 16), 256, 0, stream>>>(
        P, vt, (void*)out, 1024, 1024, 1024, (long long)L_N * L_N, (long long)D_N * L_N,
        (long long)L_N * OUTW, OUTW, slot * D_N);
  };

  // column slices within proj buffers (all x512 elements):
  // pt: [ta_kx, ta_qx, ta_vx, tv_kx, tv_qx, tv_vx, tav_k, tav_v], ld 4096
  // pa: [ta_ky, ta_qy, ta_vy, va_ky, va_qy, va_vy], ld 3072
  // pv: [va_kx, va_qx, va_vx, tv_ky, tv_qy, tv_vy], ld 3072
  // ta block (m1=txt, m2=au) -> slot 3
  attn(pa + 512 * 1, 3072, pt + 512 * 0, 4096, pt + 512 * 2, 4096, 3);  // s1: q2@k1, v1
  attn(pt + 512 * 1, 4096, pa + 512 * 0, 3072, pa + 512 * 2, 3072, 3);  // s2: q1@k2, v2
  // va block (m1=vi, m2=au) -> slot 5
  attn(pa + 512 * 4, 3072, pv + 512 * 0, 3072, pv + 512 * 2, 3072, 5);
  attn(pv + 512 * 1, 3072, pa + 512 * 3, 3072, pa + 512 * 5, 3072, 5);
  // tv block (m1=txt, m2=vi) -> slot 4
  attn(pv + 512 * 4, 3072, pt + 512 * 3, 4096, pt + 512 * 5, 4096, 4);
  attn(pt + 512 * 4, 4096, pv + 512 * 3, 3072, pv + 512 * 5, 3072, 4);

  // cross attention: x = txt, queries = av (slot 5 complete at this point)
  conv_av_k<<<8192, 256, 0, stream>>>(out, avb);
  gemm_bt<0><<<dim3(128, 4, 1), 256, 0, stream>>>(avb, wb + 20 * W_N, (void*)pav, 512, 512,
                                                  512, 0LL, 0LL, 0LL, 512, 0);
  attn(pav, 512, pt + 512 * 6, 4096, pt + 512 * 7, 4096, 6);
}